// Round 3
// baseline (427.324 us; speedup 1.0000x reference)
//
#include <hip/hip_runtime.h>
#include <cstdint>

// Problem: out = inputs @ W  (softmax over a constant axis is uniform; GAT collapses to the GEMM)
// inputs: (131072, 256) fp32, W: (256,256) fp32, out: (131072, 256) fp32.
//
// R3: persistent blocks (1/CU) + software-pipelined tile loop. R1/R2 both hit 85 us with
// all pipes <30%: per-CU exclusive times (mem 33us + LDS 20us + MFMA 8us + VALU 5us) SUM
// to the measured time -> phases were serialized (1 block/CU, waves temporally aligned).
// Here each block stages W once, then loops 4 row-tiles: next tile's A-loads issue in
// groups between MFMA k-steps, stores are fire-and-forget under the next tile's compute.

static constexpr int KDIM = 256;
static constexpr int NDIM = 256;
static constexpr int MTOT = 131072;
static constexpr int ROWS_PER_TILE = 128;
static constexpr int NBLOCKS = 256;
static constexpr int TPB = MTOT / ROWS_PER_TILE / NBLOCKS;   // 4 tiles per block

typedef __bf16 bf16x8 __attribute__((ext_vector_type(8)));
typedef float f32x4 __attribute__((ext_vector_type(4)));

__device__ __forceinline__ uint32_t f2bf_pk(float a, float b) {
    uint32_t ua = __float_as_uint(a);
    uint32_t ub = __float_as_uint(b);
    ua = ua + 0x7fffu + ((ua >> 16) & 1u);
    ub = ub + 0x7fffu + ((ub >> 16) & 1u);
    return (ua >> 16) | (ub & 0xffff0000u);
}

__device__ __forceinline__ uint4 pack2(float4 x, float4 y) {
    uint4 r;
    r.x = f2bf_pk(x.x, x.y); r.y = f2bf_pk(x.z, x.w);
    r.z = f2bf_pk(y.x, y.y); r.w = f2bf_pk(y.z, y.w);
    return r;
}

// --- kernel 1: W (k-major fp32) -> bf16 image in workspace ------------------
// 16-byte unit u = (k/8)*256 + n holds 8 k-consecutive bf16 of column n.
__global__ void wt_image(const float* __restrict__ W, unsigned short* __restrict__ img) {
    int k = blockIdx.x;
    int n = threadIdx.x;
    float v = W[k * NDIM + n];
    uint32_t u = __float_as_uint(v);
    u = u + 0x7fffu + ((u >> 16) & 1u);
    img[((size_t)((k >> 3) * NDIM + n) << 3) + (k & 7)] = (unsigned short)(u >> 16);
}

// --- kernel 2: persistent pipelined GEMM ------------------------------------
// 1024 thr = 16 waves = 8 stripes x 2 col-halves. Wave (stripe,half) computes
// rows [tile*128 + stripe*16, +16) x cols [half*128, +128). acc = 8 x f32x4.
__global__ __launch_bounds__(1024, 1)
void gat_gemm(const float* __restrict__ A, const uint4* __restrict__ img,
              float* __restrict__ C) {
    __shared__ uint4 Bs[8192];   // full W image, 128 KB

    const int tid    = threadIdx.x;
    const int lane   = tid & 63;
    const int wave   = tid >> 6;
    const int l15    = lane & 15;
    const int quad   = lane >> 4;
    const int stripe = wave >> 1;
    const int half   = wave & 1;

    // A row pointer for tile-index t (tiles strided NBLOCKS apart across blocks)
    auto aptr = [&](int t) -> const float* {
        return A + (size_t)((blockIdx.x + t * NBLOCKS) * ROWS_PER_TILE + stripe * 16 + l15) * KDIM;
    };

    // ---- prologue: issue tile-0 A loads, then stage W (A latency hides under it) ----
    float4 raw[16];
    {
        const float* p0 = aptr(0);
#pragma unroll
        for (int g = 0; g < 4; ++g) {
            const float* p = p0 + g * 64 + quad * 8;
            raw[g * 4 + 0] = *(const float4*)(p);
            raw[g * 4 + 1] = *(const float4*)(p + 4);
            raw[g * 4 + 2] = *(const float4*)(p + 32);
            raw[g * 4 + 3] = *(const float4*)(p + 36);
        }
    }
#pragma unroll
    for (int i = 0; i < 8; ++i)
        Bs[tid + i * 1024] = img[tid + i * 1024];

    uint4 cur[8];
#pragma unroll
    for (int g = 0; g < 4; ++g) {
        cur[2 * g]     = pack2(raw[g * 4 + 0], raw[g * 4 + 1]);
        cur[2 * g + 1] = pack2(raw[g * 4 + 2], raw[g * 4 + 3]);
    }

    f32x4 acc[8];
#pragma unroll
    for (int j = 0; j < 8; ++j) acc[j] = (f32x4)0.0f;

    __syncthreads();   // the only barrier

#define KSTEP(ks)                                                                 \
    {                                                                             \
        bf16x8 af = __builtin_bit_cast(bf16x8, cur[ks]);                          \
        const uint4* bb = &Bs[((ks) * 4 + quad) * 256 + half * 128 + l15];        \
        _Pragma("unroll")                                                         \
        for (int j = 0; j < 8; ++j) {                                             \
            bf16x8 bf = __builtin_bit_cast(bf16x8, bb[j * 16]);                   \
            acc[j] = __builtin_amdgcn_mfma_f32_16x16x32_bf16(af, bf, acc[j], 0, 0, 0); \
        }                                                                         \
    }

#define LOADG(g, dst)                                                             \
    {                                                                             \
        const float* p = np + (g) * 64 + quad * 8;                                \
        dst[0] = *(const float4*)(p);                                             \
        dst[1] = *(const float4*)(p + 4);                                         \
        dst[2] = *(const float4*)(p + 32);                                        \
        dst[3] = *(const float4*)(p + 36);                                        \
    }

    for (int t = 0; t < TPB; ++t) {
        const bool pf = (t < TPB - 1);
        const float* np = pf ? aptr(t + 1) : aptr(t);   // dummy self-ptr when no prefetch
        float4 g0[4], g1[4], g2[4], g3[4];

        if (pf) LOADG(0, g0)
        KSTEP(0)
        if (pf) LOADG(1, g1)
        KSTEP(1)
        if (pf) LOADG(2, g2)
        KSTEP(2)
        if (pf) LOADG(3, g3)
        KSTEP(3)
        if (pf) { cur[0] = pack2(g0[0], g0[1]); cur[1] = pack2(g0[2], g0[3]); }
        KSTEP(4)
        if (pf) { cur[2] = pack2(g1[0], g1[1]); cur[3] = pack2(g1[2], g1[3]); }
        KSTEP(5)
        if (pf) { cur[4] = pack2(g2[0], g2[1]); cur[5] = pack2(g2[2], g2[3]); }
        KSTEP(6)
        KSTEP(7)
        if (pf) { cur[6] = pack2(g3[0], g3[1]); cur[7] = pack2(g3[2], g3[3]); }

        // ---- epilogue: fire-and-forget stores, C/D layout col=l15, row=quad*4+r ----
        const size_t rbase = (size_t)((blockIdx.x + t * NBLOCKS) * ROWS_PER_TILE
                                      + stripe * 16 + quad * 4);
#pragma unroll
        for (int j = 0; j < 8; ++j) {
            const int n = half * 128 + j * 16 + l15;
#pragma unroll
            for (int r = 0; r < 4; ++r)
                C[(rbase + r) * NDIM + n] = acc[j][r];
            acc[j] = (f32x4)0.0f;
        }
    }
#undef KSTEP
#undef LOADG
}

extern "C" void kernel_launch(void* const* d_in, const int* in_sizes, int n_in,
                              void* d_out, int out_size, void* d_ws, size_t ws_size,
                              hipStream_t stream) {
    (void)in_sizes; (void)n_in; (void)out_size; (void)ws_size;
    const float* inputs = (const float*)d_in[0];
    const float* W      = (const float*)d_in[1];
    // d_in[2] ('a') is mathematically unused: softmax over a constant axis is uniform,
    // so the output is exactly inputs @ W.
    unsigned short* img = (unsigned short*)d_ws;     // 128 KB scratch
    float* out = (float*)d_out;

    hipLaunchKernelGGL(wt_image, dim3(KDIM), dim3(NDIM), 0, stream, W, img);
    hipLaunchKernelGGL(gat_gemm, dim3(NBLOCKS), dim3(1024), 0, stream,
                       inputs, (const uint4*)img, out);
}